// Round 6
// baseline (348.472 us; speedup 1.0000x reference)
//
#include <hip/hip_runtime.h>
#include <hip/hip_bf16.h>

#define NN 100000
#define NE 1600000
#define NG 128
#define FIN 128
#define HID 32
#define NCLS 10

#define NXCD 8
#define XRANGE (NN / NXCD)                   // 12500 dst nodes per XCD range
#define EG4 (NE / 4)                         // 400000 int4 edge groups

// bucket pass
#define BKB 1024
#define BGPB ((EG4 + BKB - 1) / BKB)         // int4 groups per bucket-block
#define BCAP 232768                          // NE/8 + 32768 slack (78 sigma), %4==0
#define HSLICES 128
#define H2GRID (HSLICES * NXCD)              // 1024 blocks, bid&7 = bucket/XCD

#define SCAN_B 1024
#define NB ((NN + SCAN_B - 1) / SCAN_B)      // 98

#define POOL_CHUNK 512
#define POOL_SEG 16
#define POOL_GSPAN 32
#define POOL_GRID ((NN + POOL_CHUNK - 1) / POOL_CHUNK)

// GEMM0 MFMA tiling
#define G0_NODES 64
#define G0_GRID ((NN + G0_NODES - 1) / G0_NODES)
#define XPAD 136

typedef int int4v __attribute__((ext_vector_type(4)));
typedef __attribute__((ext_vector_type(8))) short short8;
typedef __attribute__((ext_vector_type(4))) float f32x4;

__device__ inline unsigned short f2bf(float f) {
    unsigned int u = __float_as_uint(f);
    unsigned int r = u + 0x7FFFu + ((u >> 16) & 1u);   // RNE
    return (unsigned short)(r >> 16);
}
__device__ inline float bf2f(unsigned short v) {
    return __uint_as_float(((unsigned int)v) << 16);
}

// ---------------- init: zero accumulators ----------------
__global__ void k_init(int* __restrict__ counts, float* __restrict__ gsum,
                       float* __restrict__ gcnt, int* __restrict__ bcur) {
    int i = blockIdx.x * blockDim.x + threadIdx.x;
    int stride = gridDim.x * blockDim.x;
    for (int j = i; j < NN; j += stride) counts[j] = 0;
    for (int j = i; j < NG * HID; j += stride) gsum[j] = 0.f;
    for (int j = i; j < NG; j += stride) gcnt[j] = 0.f;
    if (i < NXCD) bcur[i] = 0;
}

// ------- phase 1: partition (src,dst) pairs into 8 dst-range buckets -------
__global__ void k_bucket(const int* __restrict__ src, const int* __restrict__ dst,
                         int* __restrict__ bcur, int* __restrict__ bdst,
                         int* __restrict__ bsrc) {
    __shared__ int lcnt[NXCD];
    __shared__ int lbase[NXCD];
    __shared__ int lcur[NXCD];
    const int g0 = blockIdx.x * BGPB;
    int g1 = g0 + BGPB; if (g1 > EG4) g1 = EG4;
    if (threadIdx.x < NXCD) { lcnt[threadIdx.x] = 0; lcur[threadIdx.x] = 0; }
    __syncthreads();
    // pass 1: per-block bucket counts
    for (int g = g0 + threadIdx.x; g < g1; g += 256) {
        const int4v d = *((const int4v*)dst + g);
        atomicAdd(&lcnt[d.x / XRANGE], 1);
        atomicAdd(&lcnt[d.y / XRANGE], 1);
        atomicAdd(&lcnt[d.z / XRANGE], 1);
        atomicAdd(&lcnt[d.w / XRANGE], 1);
    }
    __syncthreads();
    if (threadIdx.x < NXCD)
        lbase[threadIdx.x] = atomicAdd(&bcur[threadIdx.x], lcnt[threadIdx.x]);
    __syncthreads();
    // pass 2: write pairs into this block's chunk of each bucket (slice L2-hot)
    for (int g = g0 + threadIdx.x; g < g1; g += 256) {
        const int4v d = *((const int4v*)dst + g);
        const int4v s = *((const int4v*)src + g);
        int b, p;
        b = d.x / XRANGE; p = lbase[b] + atomicAdd(&lcur[b], 1);
        bdst[b * BCAP + p] = d.x; bsrc[b * BCAP + p] = s.x;
        b = d.y / XRANGE; p = lbase[b] + atomicAdd(&lcur[b], 1);
        bdst[b * BCAP + p] = d.y; bsrc[b * BCAP + p] = s.y;
        b = d.z / XRANGE; p = lbase[b] + atomicAdd(&lcur[b], 1);
        bdst[b * BCAP + p] = d.z; bsrc[b * BCAP + p] = s.z;
        b = d.w / XRANGE; p = lbase[b] + atomicAdd(&lcur[b], 1);
        bdst[b * BCAP + p] = d.w; bsrc[b * BCAP + p] = s.w;
    }
}

// ------- phase 2a: histogram from own bucket (XCD-local everything) -------
__global__ void k_histx2(const int* __restrict__ bdst, const int* __restrict__ bcur,
                         int* __restrict__ counts) {
    const int b = blockIdx.x & (NXCD - 1);
    const int slice = blockIdx.x >> 3;
    const int n = bcur[b];
    const int* p = bdst + b * BCAP;
    const int per = (((n + HSLICES - 1) / HSLICES) + 3) & ~3;
    const int s0 = slice * per;
    int s1 = s0 + per; if (s1 > n) s1 = n;
    for (int off = s0 + threadIdx.x * 4; off < s1; off += 1024) {
        if (off + 4 <= s1) {
            const int4v d = *(const int4v*)(p + off);
            atomicAdd(&counts[d.x], 1);
            atomicAdd(&counts[d.y], 1);
            atomicAdd(&counts[d.z], 1);
            atomicAdd(&counts[d.w], 1);
        } else {
            for (int j = off; j < s1; j++) atomicAdd(&counts[p[j]], 1);
        }
    }
}

// ---------------- scan phase A: per-block exclusive scan (+ dinv fused) --------
__global__ void k_scanA(const int* __restrict__ counts, int* __restrict__ row_ptr,
                        int* __restrict__ bsum, float* __restrict__ dinv) {
    __shared__ int lds[SCAN_B];
    int i = blockIdx.x * SCAN_B + threadIdx.x;
    int v = (i < NN) ? counts[i] : 0;
    if (i < NN) dinv[i] = rsqrtf((float)v + 1.0f);
    lds[threadIdx.x] = v;
    __syncthreads();
    int val = v;
    for (int off = 1; off < SCAN_B; off <<= 1) {
        int u = 0;
        if ((int)threadIdx.x >= off) u = lds[threadIdx.x - off];
        __syncthreads();
        if ((int)threadIdx.x >= off) { val += u; lds[threadIdx.x] = val; }
        __syncthreads();
    }
    if (i < NN) row_ptr[i] = val - v;
    if (threadIdx.x == SCAN_B - 1) bsum[blockIdx.x] = val;
}

// ---------------- scan phase B ----------------
__global__ void k_scanB(int* __restrict__ bsum) {
    __shared__ int lds[128];
    int t = threadIdx.x;
    int v = (t < NB) ? bsum[t] : 0;
    lds[t] = v;
    __syncthreads();
    int val = v;
    for (int off = 1; off < 128; off <<= 1) {
        int u = 0;
        if (t >= off) u = lds[t - off];
        __syncthreads();
        if (t >= off) { val += u; lds[t] = val; }
        __syncthreads();
    }
    if (t < NB) bsum[t] = val - v;
}

// ---------------- scan phase C ----------------
__global__ void k_scanC(int* __restrict__ row_ptr, int* __restrict__ cursor,
                        const int* __restrict__ bsum) {
    int i = blockIdx.x * SCAN_B + threadIdx.x;
    if (i < NN) {
        int r = row_ptr[i] + bsum[blockIdx.x];
        row_ptr[i] = r;
        cursor[i] = r;
    }
    if (i == 0) row_ptr[NN] = NE;
}

// ------- phase 2b: scatter from own bucket into CSR (XCD-local) -------
__global__ void k_scatx2(const int* __restrict__ bdst, const int* __restrict__ bsrc,
                         const int* __restrict__ bcur, int* __restrict__ cursor,
                         int* __restrict__ csr_src) {
    const int b = blockIdx.x & (NXCD - 1);
    const int slice = blockIdx.x >> 3;
    const int n = bcur[b];
    const int* pd = bdst + b * BCAP;
    const int* ps = bsrc + b * BCAP;
    const int per = (((n + HSLICES - 1) / HSLICES) + 3) & ~3;
    const int s0 = slice * per;
    int s1 = s0 + per; if (s1 > n) s1 = n;
    for (int off = s0 + threadIdx.x * 4; off < s1; off += 1024) {
        if (off + 4 <= s1) {
            const int4v d = *(const int4v*)(pd + off);
            const int4v s = *(const int4v*)(ps + off);
            int q0 = atomicAdd(&cursor[d.x], 1);
            int q1 = atomicAdd(&cursor[d.y], 1);
            int q2 = atomicAdd(&cursor[d.z], 1);
            int q3 = atomicAdd(&cursor[d.w], 1);
            csr_src[q0] = s.x; csr_src[q1] = s.y;
            csr_src[q2] = s.z; csr_src[q3] = s.w;
        } else {
            for (int j = off; j < s1; j++) {
                int q = atomicAdd(&cursor[pd[j]], 1);
                csr_src[q] = ps[j];
            }
        }
    }
}

// ---------------- layer-0 GEMM via bf16 MFMA: t = bf16((x @ W0) * dinv) --------
__global__ void k_gemm0(const float* __restrict__ x, const float* __restrict__ W,
                        const float* __restrict__ dinv, unsigned short* __restrict__ t) {
    __shared__ __align__(16) unsigned short x_lds[G0_NODES][XPAD];
    __shared__ __align__(16) unsigned short wt_lds[HID][XPAD];
    const int tid = threadIdx.x;
    const int node0 = blockIdx.x * G0_NODES;

#pragma unroll
    for (int r = 0; r < 8; r++) {
        int q = tid + 256 * r;
        int row = q >> 5;
        int c4 = q & 31;
        float4 xv = {0.f, 0.f, 0.f, 0.f};
        int node = node0 + row;
        if (node < NN) xv = ((const float4*)(x + (size_t)node * FIN))[c4];
        ushort4 b;
        b.x = f2bf(xv.x); b.y = f2bf(xv.y); b.z = f2bf(xv.z); b.w = f2bf(xv.w);
        *(ushort4*)&x_lds[row][c4 * 4] = b;
    }
#pragma unroll
    for (int r = 0; r < 16; r++) {
        int q = tid + 256 * r;
        int k = q >> 5, n = q & 31;
        wt_lds[n][k] = f2bf(W[q]);
    }
    __syncthreads();

    const int w = tid >> 6;
    const int lane = tid & 63;
    const int row = lane & 15;
    const int kg = lane >> 4;
    const int w16 = w * 16;

    f32x4 acc0 = {0.f, 0.f, 0.f, 0.f};
    f32x4 acc1 = {0.f, 0.f, 0.f, 0.f};
#pragma unroll
    for (int s = 0; s < 4; s++) {
        short8 a  = *(const short8*)&x_lds[w16 + row][s * 32 + kg * 8];
        short8 b0 = *(const short8*)&wt_lds[row][s * 32 + kg * 8];
        short8 b1 = *(const short8*)&wt_lds[16 + row][s * 32 + kg * 8];
        acc0 = __builtin_amdgcn_mfma_f32_16x16x32_bf16(a, b0, acc0, 0, 0, 0);
        acc1 = __builtin_amdgcn_mfma_f32_16x16x32_bf16(a, b1, acc1, 0, 0, 0);
    }

    const int f = lane & 15;
#pragma unroll
    for (int j = 0; j < 4; j++) {
        int node = node0 + w16 + kg * 4 + j;
        if (node < NN) {
            float di = dinv[node];
            t[(size_t)node * HID + f]      = f2bf(acc0[j] * di);
            t[(size_t)node * HID + 16 + f] = f2bf(acc1[j] * di);
        }
    }
}

// ---------------- hidden GEMM: t = bf16((h @ W) * dinv) ----------------
__global__ void k_gemmh(const float* __restrict__ h, const float* __restrict__ W,
                        const float* __restrict__ dinv, unsigned short* __restrict__ t) {
    __shared__ float Ws[HID * HID];
    for (int j = threadIdx.x; j < HID * HID; j += 256) Ws[j] = W[j];
    __syncthreads();
    int gid = blockIdx.x * 256 + threadIdx.x;
    int i = gid >> 5, f = gid & 31;
    if (i >= NN) return;
    const float4* hr = (const float4*)(h + (size_t)i * HID);
    float acc = 0.f;
#pragma unroll
    for (int k4 = 0; k4 < HID / 4; k4++) {
        float4 hv = hr[k4];
        int kb = k4 * 4;
        acc = fmaf(hv.x, Ws[(kb + 0) * HID + f], acc);
        acc = fmaf(hv.y, Ws[(kb + 1) * HID + f], acc);
        acc = fmaf(hv.z, Ws[(kb + 2) * HID + f], acc);
        acc = fmaf(hv.w, Ws[(kb + 3) * HID + f], acc);
    }
    t[(size_t)i * HID + f] = f2bf(acc * dinv[i]);
}

// ------- aggregation: lane = feature, bf16 rows (one 64B line per gather) -------
__global__ void k_agg(const unsigned short* __restrict__ t, const int* __restrict__ row_ptr,
                      const int* __restrict__ csr_src, const float* __restrict__ dinv,
                      const float* __restrict__ b, float* __restrict__ hout) {
    int gid = blockIdx.x * blockDim.x + threadIdx.x;
    int i = gid >> 5;                 // node
    int lane = threadIdx.x & 31;      // feature
    if (i >= NN) return;
    float acc = bf2f(t[(size_t)i * HID + lane]);    // self term
    const int beg = row_ptr[i], end = row_ptr[i + 1];
    int e = beg;
    for (; e + 8 <= end; e += 8) {
        int s0 = csr_src[e + 0];
        int s1 = csr_src[e + 1];
        int s2 = csr_src[e + 2];
        int s3 = csr_src[e + 3];
        int s4 = csr_src[e + 4];
        int s5 = csr_src[e + 5];
        int s6 = csr_src[e + 6];
        int s7 = csr_src[e + 7];
        unsigned short u0 = t[(size_t)s0 * HID + lane];
        unsigned short u1 = t[(size_t)s1 * HID + lane];
        unsigned short u2 = t[(size_t)s2 * HID + lane];
        unsigned short u3 = t[(size_t)s3 * HID + lane];
        unsigned short u4 = t[(size_t)s4 * HID + lane];
        unsigned short u5 = t[(size_t)s5 * HID + lane];
        unsigned short u6 = t[(size_t)s6 * HID + lane];
        unsigned short u7 = t[(size_t)s7 * HID + lane];
        acc += ((bf2f(u0) + bf2f(u1)) + (bf2f(u2) + bf2f(u3)))
             + ((bf2f(u4) + bf2f(u5)) + (bf2f(u6) + bf2f(u7)));
    }
    for (; e + 4 <= end; e += 4) {
        int s0 = csr_src[e + 0];
        int s1 = csr_src[e + 1];
        int s2 = csr_src[e + 2];
        int s3 = csr_src[e + 3];
        unsigned short u0 = t[(size_t)s0 * HID + lane];
        unsigned short u1 = t[(size_t)s1 * HID + lane];
        unsigned short u2 = t[(size_t)s2 * HID + lane];
        unsigned short u3 = t[(size_t)s3 * HID + lane];
        acc += (bf2f(u0) + bf2f(u1)) + (bf2f(u2) + bf2f(u3));
    }
    for (; e < end; e++) {
        acc += bf2f(t[(size_t)csr_src[e] * HID + lane]);
    }
    float r = fmaf(acc, dinv[i], b[lane]);
    hout[(size_t)i * HID + lane] = fmaxf(r, 0.f);
}

// ---------------- pooling: register-segment accumulate -> LDS bins ----------
__global__ void k_pool2(const float* __restrict__ h, const int* __restrict__ batch,
                        float* __restrict__ gsum, float* __restrict__ gcnt) {
    __shared__ float lacc[POOL_GSPAN][HID];
    __shared__ float lcnt[POOL_GSPAN];
    __shared__ int s_gmin;
    const int chunk_start = blockIdx.x * POOL_CHUNK;

    for (int j = threadIdx.x; j < POOL_GSPAN * HID; j += 256) ((float*)lacc)[j] = 0.f;
    if (threadIdx.x < POOL_GSPAN) lcnt[threadIdx.x] = 0.f;
    if (threadIdx.x == 0) {
        int cs = chunk_start < NN ? chunk_start : NN - 1;
        s_gmin = batch[cs];
    }
    __syncthreads();
    const int gmin = s_gmin;

    const int seg = threadIdx.x >> 3;
    const int l = (threadIdx.x & 7) * 4;
    const int i0 = chunk_start + seg * POOL_SEG;

    float4 acc = {0.f, 0.f, 0.f, 0.f};
    float cnt = 0.f;
    int cur_g = -1;

    for (int k = 0; k < POOL_SEG; k++) {
        int i = i0 + k;
        if (i >= NN) break;
        int g = batch[i];
        if (g != cur_g) {
            if (cur_g >= 0) {
                int bin = cur_g - gmin;
                if (bin >= 0 && bin < POOL_GSPAN) {
                    atomicAdd(&lacc[bin][l + 0], acc.x);
                    atomicAdd(&lacc[bin][l + 1], acc.y);
                    atomicAdd(&lacc[bin][l + 2], acc.z);
                    atomicAdd(&lacc[bin][l + 3], acc.w);
                    if (l == 0) atomicAdd(&lcnt[bin], cnt);
                } else {
                    atomicAdd(&gsum[cur_g * HID + l + 0], acc.x);
                    atomicAdd(&gsum[cur_g * HID + l + 1], acc.y);
                    atomicAdd(&gsum[cur_g * HID + l + 2], acc.z);
                    atomicAdd(&gsum[cur_g * HID + l + 3], acc.w);
                    if (l == 0) atomicAdd(&gcnt[cur_g], cnt);
                }
            }
            cur_g = g;
            acc.x = acc.y = acc.z = acc.w = 0.f;
            cnt = 0.f;
        }
        const float4 v = *(const float4*)&h[(size_t)i * HID + l];
        acc.x += v.x; acc.y += v.y; acc.z += v.z; acc.w += v.w;
        cnt += 1.f;
    }
    if (cur_g >= 0) {
        int bin = cur_g - gmin;
        if (bin >= 0 && bin < POOL_GSPAN) {
            atomicAdd(&lacc[bin][l + 0], acc.x);
            atomicAdd(&lacc[bin][l + 1], acc.y);
            atomicAdd(&lacc[bin][l + 2], acc.z);
            atomicAdd(&lacc[bin][l + 3], acc.w);
            if (l == 0) atomicAdd(&lcnt[bin], cnt);
        } else {
            atomicAdd(&gsum[cur_g * HID + l + 0], acc.x);
            atomicAdd(&gsum[cur_g * HID + l + 1], acc.y);
            atomicAdd(&gsum[cur_g * HID + l + 2], acc.z);
            atomicAdd(&gsum[cur_g * HID + l + 3], acc.w);
            if (l == 0) atomicAdd(&gcnt[cur_g], cnt);
        }
    }
    __syncthreads();

    for (int j = threadIdx.x; j < POOL_GSPAN * HID; j += 256) {
        int bin = j / HID, f = j % HID;
        int g = gmin + bin;
        float v = lacc[bin][f];
        if (g < NG && v != 0.f) atomicAdd(&gsum[g * HID + f], v);
    }
    if (threadIdx.x < POOL_GSPAN) {
        int g = gmin + threadIdx.x;
        float c = lcnt[threadIdx.x];
        if (g < NG && c != 0.f) atomicAdd(&gcnt[g], c);
    }
}

// ---------------- classifier + log_softmax ----------------
__global__ void k_classify(const float* __restrict__ gsum, const float* __restrict__ gcnt,
                           const float* __restrict__ Wl, const float* __restrict__ bl,
                           float* __restrict__ out) {
    __shared__ float w[HID * NCLS];
    __shared__ float bb[NCLS];
    int t = threadIdx.x;
    for (int j = t; j < HID * NCLS; j += blockDim.x) w[j] = Wl[j];
    if (t < NCLS) bb[t] = bl[t];
    __syncthreads();
    if (t >= NG) return;
    float c = gcnt[t];
    c = c > 1.f ? c : 1.f;
    float p[HID];
#pragma unroll
    for (int k = 0; k < HID; k++) p[k] = gsum[t * HID + k] / c;
    float lg[NCLS];
    float m = -1e30f;
#pragma unroll
    for (int c2 = 0; c2 < NCLS; c2++) {
        float a = bb[c2];
#pragma unroll
        for (int k = 0; k < HID; k++) a = fmaf(p[k], w[k * NCLS + c2], a);
        a = a > 0.f ? a : 0.f;
        lg[c2] = a;
        m = fmaxf(m, a);
    }
    float s = 0.f;
#pragma unroll
    for (int c2 = 0; c2 < NCLS; c2++) s += expf(lg[c2] - m);
    float ls = logf(s);
#pragma unroll
    for (int c2 = 0; c2 < NCLS; c2++) out[t * NCLS + c2] = lg[c2] - m - ls;
}

extern "C" void kernel_launch(void* const* d_in, const int* in_sizes, int n_in,
                              void* d_out, int out_size, void* d_ws, size_t ws_size,
                              hipStream_t stream) {
    const float* x  = (const float*)d_in[0];
    const int* ei   = (const int*)d_in[1];
    const int* batch = (const int*)d_in[2];
    const float* W0 = (const float*)d_in[3];
    const float* b0 = (const float*)d_in[4];
    const float* W1 = (const float*)d_in[5];
    const float* b1 = (const float*)d_in[6];
    const float* W2 = (const float*)d_in[7];
    const float* b2 = (const float*)d_in[8];
    const float* Wl = (const float*)d_in[9];
    const float* bl = (const float*)d_in[10];
    float* out = (float*)d_out;

    const int* esrc = ei;
    const int* edst = ei + NE;

    char* ws = (char*)d_ws;
    size_t off = 0;
    auto alloc = [&](size_t bytes) -> void* {
        void* p = ws + off;
        off = (off + bytes + 511) & ~(size_t)511;
        return p;
    };
    int*   counts  = (int*)alloc(NN * sizeof(int));
    int*   row_ptr = (int*)alloc((NN + 1) * sizeof(int));
    int*   cursor  = (int*)alloc(NN * sizeof(int));
    float* dinv    = (float*)alloc(NN * sizeof(float));
    int*   bsum    = (int*)alloc(256 * sizeof(int));
    int*   bcur    = (int*)alloc(64 * sizeof(int));
    int*   csr_src = (int*)alloc(NE * sizeof(int));
    unsigned short* tbuf = (unsigned short*)alloc((size_t)NN * HID * sizeof(unsigned short));
    float* hA      = (float*)alloc((size_t)NN * HID * sizeof(float));
    float* hB      = (float*)alloc((size_t)NN * HID * sizeof(float));
    float* gsum    = (float*)alloc(NG * HID * sizeof(float));
    float* gcnt    = (float*)alloc(NG * sizeof(float));
    (void)ws_size; (void)in_sizes; (void)n_in; (void)out_size;

    // bucket arrays alias the (tbuf,hA) region — dead until CSR build completes.
    // tbuf(6.4MB)+hA(12.8MB) are contiguous (both sizes %512==0); need 14.9MB.
    int* bdst = (int*)tbuf;
    int* bsrc = bdst + (size_t)NXCD * BCAP;

    // ---- CSR build: bucket -> hist -> scan -> scatter ----
    k_init<<<256, 256, 0, stream>>>(counts, gsum, gcnt, bcur);
    k_bucket<<<BKB, 256, 0, stream>>>(esrc, edst, bcur, bdst, bsrc);
    k_histx2<<<H2GRID, 256, 0, stream>>>(bdst, bcur, counts);
    k_scanA<<<NB, SCAN_B, 0, stream>>>(counts, row_ptr, bsum, dinv);
    k_scanB<<<1, 128, 0, stream>>>(bsum);
    k_scanC<<<NB, SCAN_B, 0, stream>>>(row_ptr, cursor, bsum);
    k_scatx2<<<H2GRID, 256, 0, stream>>>(bdst, bsrc, bcur, cursor, csr_src);

    const int gemm_grid = (NN * HID + 255) / 256;
    const int agg_grid = (NN * 32 + 255) / 256;

    // ---- layer 0 (MFMA) ----
    k_gemm0<<<G0_GRID, 256, 0, stream>>>(x, W0, dinv, tbuf);
    k_agg<<<agg_grid, 256, 0, stream>>>(tbuf, row_ptr, csr_src, dinv, b0, hA);
    // ---- layer 1 ----
    k_gemmh<<<gemm_grid, 256, 0, stream>>>(hA, W1, dinv, tbuf);
    k_agg<<<agg_grid, 256, 0, stream>>>(tbuf, row_ptr, csr_src, dinv, b1, hB);
    // ---- layer 2 ----
    k_gemmh<<<gemm_grid, 256, 0, stream>>>(hB, W2, dinv, tbuf);
    k_agg<<<agg_grid, 256, 0, stream>>>(tbuf, row_ptr, csr_src, dinv, b2, hA);

    // ---- pooling + classifier ----
    k_pool2<<<POOL_GRID, 256, 0, stream>>>(hA, batch, gsum, gcnt);
    k_classify<<<1, 128, 0, stream>>>(gsum, gcnt, Wl, bl, out);
}

// Round 7
// 262.711 us; speedup vs baseline: 1.3265x; 1.3265x over previous
//
#include <hip/hip_runtime.h>
#include <hip/hip_bf16.h>

#define NN 100000
#define NE 1600000
#define NG 128
#define FIN 128
#define HID 32
#define NCLS 10

#define EG4 (NE / 4)           // 400000 int4 edge groups

// atomic-free CSR build
#define NSL 32                 // edge-list slices
#define GPS (EG4 / NSL)        // 12500 int4 groups per slice
#define RS 8                   // node sub-ranges (== NXCD, bid&7 -> XCD-local csr writes)
#define SUBN (NN / RS)         // 12500 nodes per range -> 50KB LDS counters
#define CSRGRID (RS * NSL)     // 256 blocks

#define SCAN_B 1024
#define NB ((NN + SCAN_B - 1) / SCAN_B)      // 98

#define POOL_CHUNK 512
#define POOL_SEG 16
#define POOL_GSPAN 32
#define POOL_GRID ((NN + POOL_CHUNK - 1) / POOL_CHUNK)

// GEMM0 MFMA tiling
#define G0_NODES 64
#define G0_GRID ((NN + G0_NODES - 1) / G0_NODES)
#define XPAD 136

typedef int int4v __attribute__((ext_vector_type(4)));
typedef __attribute__((ext_vector_type(8))) short short8;
typedef __attribute__((ext_vector_type(4))) float f32x4;

__device__ inline unsigned short f2bf(float f) {
    unsigned int u = __float_as_uint(f);
    unsigned int r = u + 0x7FFFu + ((u >> 16) & 1u);   // RNE
    return (unsigned short)(r >> 16);
}
__device__ inline float bf2f(unsigned short v) {
    return __uint_as_float(((unsigned int)v) << 16);
}

// ---------------- init: zero pooling accumulators ----------------
__global__ void k_init(float* __restrict__ gsum, float* __restrict__ gcnt) {
    int i = blockIdx.x * blockDim.x + threadIdx.x;
    if (i < NG * HID) gsum[i] = 0.f;
    if (i < NG) gcnt[i] = 0.f;
}

// ------- hist: block (r,s) counts its node-range over its edge slice in LDS,
//         direct-stores per-slice partial counts. ZERO global atomics. -------
__global__ void k_hist3(const int* __restrict__ dst, int* __restrict__ partial) {
    const int r = blockIdx.x & (RS - 1);
    const int s = blockIdx.x >> 3;
    const int node0 = r * SUBN;
    __shared__ int lcnt[SUBN];                 // 50 KB
    for (int k = threadIdx.x; k < SUBN; k += 256) lcnt[k] = 0;
    __syncthreads();
    const int g1 = (s + 1) * GPS;
    for (int g = s * GPS + threadIdx.x; g < g1; g += 256) {
        const int4v d = *((const int4v*)dst + g);
        unsigned k;
        k = (unsigned)(d.x - node0); if (k < SUBN) atomicAdd(&lcnt[k], 1);
        k = (unsigned)(d.y - node0); if (k < SUBN) atomicAdd(&lcnt[k], 1);
        k = (unsigned)(d.z - node0); if (k < SUBN) atomicAdd(&lcnt[k], 1);
        k = (unsigned)(d.w - node0); if (k < SUBN) atomicAdd(&lcnt[k], 1);
    }
    __syncthreads();
    for (int k = threadIdx.x; k < SUBN; k += 256)
        partial[s * NN + node0 + k] = lcnt[k];   // disjoint -> plain store
}

// ------- scanA: fold 32 partials/node -> total (+ in-place exclusive prefix
//         over slices), dinv, block-exclusive scan of totals -------
__global__ void k_scanA(int* __restrict__ partial, int* __restrict__ row_ptr,
                        int* __restrict__ bsum, float* __restrict__ dinv) {
    __shared__ int lds[SCAN_B];
    int i = blockIdx.x * SCAN_B + threadIdx.x;
    int v = 0;
    if (i < NN) {
        int run = 0;
#pragma unroll
        for (int s = 0; s < NSL; s++) {
            int c = partial[s * NN + i];
            partial[s * NN + i] = run;           // exclusive prefix (per node)
            run += c;
        }
        v = run;
        dinv[i] = rsqrtf((float)v + 1.0f);
    }
    lds[threadIdx.x] = v;
    __syncthreads();
    int val = v;
    for (int off = 1; off < SCAN_B; off <<= 1) {
        int u = 0;
        if ((int)threadIdx.x >= off) u = lds[threadIdx.x - off];
        __syncthreads();
        if ((int)threadIdx.x >= off) { val += u; lds[threadIdx.x] = val; }
        __syncthreads();
    }
    if (i < NN) row_ptr[i] = val - v;
    if (threadIdx.x == SCAN_B - 1) bsum[blockIdx.x] = val;
}

// ---------------- scanB: scan block sums ----------------
__global__ void k_scanB(int* __restrict__ bsum) {
    __shared__ int lds[128];
    int t = threadIdx.x;
    int v = (t < NB) ? bsum[t] : 0;
    lds[t] = v;
    __syncthreads();
    int val = v;
    for (int off = 1; off < 128; off <<= 1) {
        int u = 0;
        if (t >= off) u = lds[t - off];
        __syncthreads();
        if (t >= off) { val += u; lds[t] = val; }
        __syncthreads();
    }
    if (t < NB) bsum[t] = val - v;
}

// ---------------- scanC: add block offsets ----------------
__global__ void k_scanC(int* __restrict__ row_ptr, const int* __restrict__ bsum) {
    int i = blockIdx.x * SCAN_B + threadIdx.x;
    if (i < NN) row_ptr[i] += bsum[blockIdx.x];
    if (i == 0) row_ptr[NN] = NE;
}

// ------- scatter: LDS cursor = row_ptr + slice-prefix; per-edge position via
//         LDS atomic only; csr writes XCD-local (bid&7 == node range). -------
__global__ void k_scat3(const int* __restrict__ src, const int* __restrict__ dst,
                        const int* __restrict__ row_ptr, const int* __restrict__ pref,
                        int* __restrict__ csr_src) {
    const int r = blockIdx.x & (RS - 1);
    const int s = blockIdx.x >> 3;
    const int node0 = r * SUBN;
    __shared__ int lcur[SUBN];                 // 50 KB
    for (int k = threadIdx.x; k < SUBN; k += 256)
        lcur[k] = row_ptr[node0 + k] + pref[s * NN + node0 + k];
    __syncthreads();
    const int g1 = (s + 1) * GPS;
    for (int g = s * GPS + threadIdx.x; g < g1; g += 256) {
        const int4v d = *((const int4v*)dst + g);
        const int4v sx = *((const int4v*)src + g);
        unsigned k;
        k = (unsigned)(d.x - node0); if (k < SUBN) { int p = atomicAdd(&lcur[k], 1); csr_src[p] = sx.x; }
        k = (unsigned)(d.y - node0); if (k < SUBN) { int p = atomicAdd(&lcur[k], 1); csr_src[p] = sx.y; }
        k = (unsigned)(d.z - node0); if (k < SUBN) { int p = atomicAdd(&lcur[k], 1); csr_src[p] = sx.z; }
        k = (unsigned)(d.w - node0); if (k < SUBN) { int p = atomicAdd(&lcur[k], 1); csr_src[p] = sx.w; }
    }
}

// ---------------- layer-0 GEMM via bf16 MFMA: t = bf16((x @ W0) * dinv) --------
__global__ void k_gemm0(const float* __restrict__ x, const float* __restrict__ W,
                        const float* __restrict__ dinv, unsigned short* __restrict__ t) {
    __shared__ __align__(16) unsigned short x_lds[G0_NODES][XPAD];
    __shared__ __align__(16) unsigned short wt_lds[HID][XPAD];
    const int tid = threadIdx.x;
    const int node0 = blockIdx.x * G0_NODES;

#pragma unroll
    for (int r = 0; r < 8; r++) {
        int q = tid + 256 * r;
        int row = q >> 5;
        int c4 = q & 31;
        float4 xv = {0.f, 0.f, 0.f, 0.f};
        int node = node0 + row;
        if (node < NN) xv = ((const float4*)(x + (size_t)node * FIN))[c4];
        ushort4 b;
        b.x = f2bf(xv.x); b.y = f2bf(xv.y); b.z = f2bf(xv.z); b.w = f2bf(xv.w);
        *(ushort4*)&x_lds[row][c4 * 4] = b;
    }
#pragma unroll
    for (int r = 0; r < 16; r++) {
        int q = tid + 256 * r;
        int k = q >> 5, n = q & 31;
        wt_lds[n][k] = f2bf(W[q]);
    }
    __syncthreads();

    const int w = tid >> 6;
    const int lane = tid & 63;
    const int row = lane & 15;
    const int kg = lane >> 4;
    const int w16 = w * 16;

    f32x4 acc0 = {0.f, 0.f, 0.f, 0.f};
    f32x4 acc1 = {0.f, 0.f, 0.f, 0.f};
#pragma unroll
    for (int s = 0; s < 4; s++) {
        short8 a  = *(const short8*)&x_lds[w16 + row][s * 32 + kg * 8];
        short8 b0 = *(const short8*)&wt_lds[row][s * 32 + kg * 8];
        short8 b1 = *(const short8*)&wt_lds[16 + row][s * 32 + kg * 8];
        acc0 = __builtin_amdgcn_mfma_f32_16x16x32_bf16(a, b0, acc0, 0, 0, 0);
        acc1 = __builtin_amdgcn_mfma_f32_16x16x32_bf16(a, b1, acc1, 0, 0, 0);
    }

    const int f = lane & 15;
#pragma unroll
    for (int j = 0; j < 4; j++) {
        int node = node0 + w16 + kg * 4 + j;
        if (node < NN) {
            float di = dinv[node];
            t[(size_t)node * HID + f]      = f2bf(acc0[j] * di);
            t[(size_t)node * HID + 16 + f] = f2bf(acc1[j] * di);
        }
    }
}

// ---------------- hidden GEMM: t = bf16((h @ W) * dinv) ----------------
__global__ void k_gemmh(const float* __restrict__ h, const float* __restrict__ W,
                        const float* __restrict__ dinv, unsigned short* __restrict__ t) {
    __shared__ float Ws[HID * HID];
    for (int j = threadIdx.x; j < HID * HID; j += 256) Ws[j] = W[j];
    __syncthreads();
    int gid = blockIdx.x * 256 + threadIdx.x;
    int i = gid >> 5, f = gid & 31;
    if (i >= NN) return;
    const float4* hr = (const float4*)(h + (size_t)i * HID);
    float acc = 0.f;
#pragma unroll
    for (int k4 = 0; k4 < HID / 4; k4++) {
        float4 hv = hr[k4];
        int kb = k4 * 4;
        acc = fmaf(hv.x, Ws[(kb + 0) * HID + f], acc);
        acc = fmaf(hv.y, Ws[(kb + 1) * HID + f], acc);
        acc = fmaf(hv.z, Ws[(kb + 2) * HID + f], acc);
        acc = fmaf(hv.w, Ws[(kb + 3) * HID + f], acc);
    }
    t[(size_t)i * HID + f] = f2bf(acc * dinv[i]);
}

// ------- aggregation: lane = feature, bf16 rows (one 64B line per gather) -------
__global__ void k_agg(const unsigned short* __restrict__ t, const int* __restrict__ row_ptr,
                      const int* __restrict__ csr_src, const float* __restrict__ dinv,
                      const float* __restrict__ b, float* __restrict__ hout) {
    int gid = blockIdx.x * blockDim.x + threadIdx.x;
    int i = gid >> 5;                 // node
    int lane = threadIdx.x & 31;      // feature
    if (i >= NN) return;
    float acc = bf2f(t[(size_t)i * HID + lane]);    // self term
    const int beg = row_ptr[i], end = row_ptr[i + 1];
    int e = beg;
    for (; e + 8 <= end; e += 8) {
        int s0 = csr_src[e + 0];
        int s1 = csr_src[e + 1];
        int s2 = csr_src[e + 2];
        int s3 = csr_src[e + 3];
        int s4 = csr_src[e + 4];
        int s5 = csr_src[e + 5];
        int s6 = csr_src[e + 6];
        int s7 = csr_src[e + 7];
        unsigned short u0 = t[(size_t)s0 * HID + lane];
        unsigned short u1 = t[(size_t)s1 * HID + lane];
        unsigned short u2 = t[(size_t)s2 * HID + lane];
        unsigned short u3 = t[(size_t)s3 * HID + lane];
        unsigned short u4 = t[(size_t)s4 * HID + lane];
        unsigned short u5 = t[(size_t)s5 * HID + lane];
        unsigned short u6 = t[(size_t)s6 * HID + lane];
        unsigned short u7 = t[(size_t)s7 * HID + lane];
        acc += ((bf2f(u0) + bf2f(u1)) + (bf2f(u2) + bf2f(u3)))
             + ((bf2f(u4) + bf2f(u5)) + (bf2f(u6) + bf2f(u7)));
    }
    for (; e + 4 <= end; e += 4) {
        int s0 = csr_src[e + 0];
        int s1 = csr_src[e + 1];
        int s2 = csr_src[e + 2];
        int s3 = csr_src[e + 3];
        unsigned short u0 = t[(size_t)s0 * HID + lane];
        unsigned short u1 = t[(size_t)s1 * HID + lane];
        unsigned short u2 = t[(size_t)s2 * HID + lane];
        unsigned short u3 = t[(size_t)s3 * HID + lane];
        acc += (bf2f(u0) + bf2f(u1)) + (bf2f(u2) + bf2f(u3));
    }
    for (; e < end; e++) {
        acc += bf2f(t[(size_t)csr_src[e] * HID + lane]);
    }
    float r = fmaf(acc, dinv[i], b[lane]);
    hout[(size_t)i * HID + lane] = fmaxf(r, 0.f);
}

// ---------------- pooling: register-segment accumulate -> LDS bins ----------
__global__ void k_pool2(const float* __restrict__ h, const int* __restrict__ batch,
                        float* __restrict__ gsum, float* __restrict__ gcnt) {
    __shared__ float lacc[POOL_GSPAN][HID];
    __shared__ float lcnt[POOL_GSPAN];
    __shared__ int s_gmin;
    const int chunk_start = blockIdx.x * POOL_CHUNK;

    for (int j = threadIdx.x; j < POOL_GSPAN * HID; j += 256) ((float*)lacc)[j] = 0.f;
    if (threadIdx.x < POOL_GSPAN) lcnt[threadIdx.x] = 0.f;
    if (threadIdx.x == 0) {
        int cs = chunk_start < NN ? chunk_start : NN - 1;
        s_gmin = batch[cs];
    }
    __syncthreads();
    const int gmin = s_gmin;

    const int seg = threadIdx.x >> 3;
    const int l = (threadIdx.x & 7) * 4;
    const int i0 = chunk_start + seg * POOL_SEG;

    float4 acc = {0.f, 0.f, 0.f, 0.f};
    float cnt = 0.f;
    int cur_g = -1;

    for (int k = 0; k < POOL_SEG; k++) {
        int i = i0 + k;
        if (i >= NN) break;
        int g = batch[i];
        if (g != cur_g) {
            if (cur_g >= 0) {
                int bin = cur_g - gmin;
                if (bin >= 0 && bin < POOL_GSPAN) {
                    atomicAdd(&lacc[bin][l + 0], acc.x);
                    atomicAdd(&lacc[bin][l + 1], acc.y);
                    atomicAdd(&lacc[bin][l + 2], acc.z);
                    atomicAdd(&lacc[bin][l + 3], acc.w);
                    if (l == 0) atomicAdd(&lcnt[bin], cnt);
                } else {
                    atomicAdd(&gsum[cur_g * HID + l + 0], acc.x);
                    atomicAdd(&gsum[cur_g * HID + l + 1], acc.y);
                    atomicAdd(&gsum[cur_g * HID + l + 2], acc.z);
                    atomicAdd(&gsum[cur_g * HID + l + 3], acc.w);
                    if (l == 0) atomicAdd(&gcnt[cur_g], cnt);
                }
            }
            cur_g = g;
            acc.x = acc.y = acc.z = acc.w = 0.f;
            cnt = 0.f;
        }
        const float4 v = *(const float4*)&h[(size_t)i * HID + l];
        acc.x += v.x; acc.y += v.y; acc.z += v.z; acc.w += v.w;
        cnt += 1.f;
    }
    if (cur_g >= 0) {
        int bin = cur_g - gmin;
        if (bin >= 0 && bin < POOL_GSPAN) {
            atomicAdd(&lacc[bin][l + 0], acc.x);
            atomicAdd(&lacc[bin][l + 1], acc.y);
            atomicAdd(&lacc[bin][l + 2], acc.z);
            atomicAdd(&lacc[bin][l + 3], acc.w);
            if (l == 0) atomicAdd(&lcnt[bin], cnt);
        } else {
            atomicAdd(&gsum[cur_g * HID + l + 0], acc.x);
            atomicAdd(&gsum[cur_g * HID + l + 1], acc.y);
            atomicAdd(&gsum[cur_g * HID + l + 2], acc.z);
            atomicAdd(&gsum[cur_g * HID + l + 3], acc.w);
            if (l == 0) atomicAdd(&gcnt[cur_g], cnt);
        }
    }
    __syncthreads();

    for (int j = threadIdx.x; j < POOL_GSPAN * HID; j += 256) {
        int bin = j / HID, f = j % HID;
        int g = gmin + bin;
        float v = lacc[bin][f];
        if (g < NG && v != 0.f) atomicAdd(&gsum[g * HID + f], v);
    }
    if (threadIdx.x < POOL_GSPAN) {
        int g = gmin + threadIdx.x;
        float c = lcnt[threadIdx.x];
        if (g < NG && c != 0.f) atomicAdd(&gcnt[g], c);
    }
}

// ---------------- classifier + log_softmax ----------------
__global__ void k_classify(const float* __restrict__ gsum, const float* __restrict__ gcnt,
                           const float* __restrict__ Wl, const float* __restrict__ bl,
                           float* __restrict__ out) {
    __shared__ float w[HID * NCLS];
    __shared__ float bb[NCLS];
    int t = threadIdx.x;
    for (int j = t; j < HID * NCLS; j += blockDim.x) w[j] = Wl[j];
    if (t < NCLS) bb[t] = bl[t];
    __syncthreads();
    if (t >= NG) return;
    float c = gcnt[t];
    c = c > 1.f ? c : 1.f;
    float p[HID];
#pragma unroll
    for (int k = 0; k < HID; k++) p[k] = gsum[t * HID + k] / c;
    float lg[NCLS];
    float m = -1e30f;
#pragma unroll
    for (int c2 = 0; c2 < NCLS; c2++) {
        float a = bb[c2];
#pragma unroll
        for (int k = 0; k < HID; k++) a = fmaf(p[k], w[k * NCLS + c2], a);
        a = a > 0.f ? a : 0.f;
        lg[c2] = a;
        m = fmaxf(m, a);
    }
    float s = 0.f;
#pragma unroll
    for (int c2 = 0; c2 < NCLS; c2++) s += expf(lg[c2] - m);
    float ls = logf(s);
#pragma unroll
    for (int c2 = 0; c2 < NCLS; c2++) out[t * NCLS + c2] = lg[c2] - m - ls;
}

extern "C" void kernel_launch(void* const* d_in, const int* in_sizes, int n_in,
                              void* d_out, int out_size, void* d_ws, size_t ws_size,
                              hipStream_t stream) {
    const float* x  = (const float*)d_in[0];
    const int* ei   = (const int*)d_in[1];
    const int* batch = (const int*)d_in[2];
    const float* W0 = (const float*)d_in[3];
    const float* b0 = (const float*)d_in[4];
    const float* W1 = (const float*)d_in[5];
    const float* b1 = (const float*)d_in[6];
    const float* W2 = (const float*)d_in[7];
    const float* b2 = (const float*)d_in[8];
    const float* Wl = (const float*)d_in[9];
    const float* bl = (const float*)d_in[10];
    float* out = (float*)d_out;

    const int* esrc = ei;
    const int* edst = ei + NE;

    char* ws = (char*)d_ws;
    size_t off = 0;
    auto alloc = [&](size_t bytes) -> void* {
        void* p = ws + off;
        off = (off + bytes + 511) & ~(size_t)511;
        return p;
    };
    int*   row_ptr = (int*)alloc((NN + 1) * sizeof(int));
    float* dinv    = (float*)alloc(NN * sizeof(float));
    int*   bsum    = (int*)alloc(256 * sizeof(int));
    int*   csr_src = (int*)alloc(NE * sizeof(int));
    unsigned short* tbuf = (unsigned short*)alloc((size_t)NN * HID * sizeof(unsigned short));
    float* hA      = (float*)alloc((size_t)NN * HID * sizeof(float));
    float* hB      = (float*)alloc((size_t)NN * HID * sizeof(float));
    float* gsum    = (float*)alloc(NG * HID * sizeof(float));
    float* gcnt    = (float*)alloc(NG * sizeof(float));
    (void)ws_size; (void)in_sizes; (void)n_in; (void)out_size;

    // partial/pref array [NSL][NN] (12.8 MB) aliases (tbuf,hA) — dead until
    // CSR build completes; tbuf is only written from k_gemm0 onward.
    int* partial = (int*)tbuf;

    // ---- CSR build: zero per-edge global atomics ----
    k_init<<<17, 256, 0, stream>>>(gsum, gcnt);
    k_hist3<<<CSRGRID, 256, 0, stream>>>(edst, partial);
    k_scanA<<<NB, SCAN_B, 0, stream>>>(partial, row_ptr, bsum, dinv);
    k_scanB<<<1, 128, 0, stream>>>(bsum);
    k_scanC<<<NB, SCAN_B, 0, stream>>>(row_ptr, bsum);
    k_scat3<<<CSRGRID, 256, 0, stream>>>(esrc, edst, row_ptr, partial, csr_src);

    const int gemm_grid = (NN * HID + 255) / 256;
    const int agg_grid = (NN * 32 + 255) / 256;

    // ---- layer 0 (MFMA) ----
    k_gemm0<<<G0_GRID, 256, 0, stream>>>(x, W0, dinv, tbuf);
    k_agg<<<agg_grid, 256, 0, stream>>>(tbuf, row_ptr, csr_src, dinv, b0, hA);
    // ---- layer 1 ----
    k_gemmh<<<gemm_grid, 256, 0, stream>>>(hA, W1, dinv, tbuf);
    k_agg<<<agg_grid, 256, 0, stream>>>(tbuf, row_ptr, csr_src, dinv, b1, hB);
    // ---- layer 2 ----
    k_gemmh<<<gemm_grid, 256, 0, stream>>>(hB, W2, dinv, tbuf);
    k_agg<<<agg_grid, 256, 0, stream>>>(tbuf, row_ptr, csr_src, dinv, b2, hA);

    // ---- pooling + classifier ----
    k_pool2<<<POOL_GRID, 256, 0, stream>>>(hA, batch, gsum, gcnt);
    k_classify<<<1, 128, 0, stream>>>(gsum, gcnt, Wl, bl, out);
}

// Round 8
// 235.675 us; speedup vs baseline: 1.4786x; 1.1147x over previous
//
#include <hip/hip_runtime.h>
#include <hip/hip_bf16.h>

#define NN 100000
#define NE 1600000
#define NG 128
#define FIN 128
#define HID 32
#define NCLS 10

#define EG4 (NE / 4)           // 400000 int4 edge groups

// atomic-free CSR build
#define NSL 32                 // edge-list slices
#define GPS (EG4 / NSL)        // 12500 int4 groups per slice
#define RS 8                   // node sub-ranges (== NXCD, bid&7 -> XCD-local csr writes)
#define SUBN (NN / RS)         // 12500 nodes per range -> 50KB LDS counters
#define CSRGRID (RS * NSL)     // 256 blocks
#define CSR_T 1024             // 16 waves/CU -> latency hiding

#define SCAN_B 1024
#define NB ((NN + SCAN_B - 1) / SCAN_B)      // 98

#define POOL_CHUNK 512
#define POOL_SEG 16
#define POOL_GSPAN 32
#define POOL_GRID ((NN + POOL_CHUNK - 1) / POOL_CHUNK)

// GEMM0 MFMA tiling
#define G0_NODES 64
#define G0_GRID ((NN + G0_NODES - 1) / G0_NODES)
#define XPAD 136

typedef int int4v __attribute__((ext_vector_type(4)));
typedef __attribute__((ext_vector_type(8))) short short8;
typedef __attribute__((ext_vector_type(4))) float f32x4;

__device__ inline unsigned short f2bf(float f) {
    unsigned int u = __float_as_uint(f);
    unsigned int r = u + 0x7FFFu + ((u >> 16) & 1u);   // RNE
    return (unsigned short)(r >> 16);
}
__device__ inline float bf2f(unsigned short v) {
    return __uint_as_float(((unsigned int)v) << 16);
}

// ---------------- init: zero pooling accumulators ----------------
__global__ void k_init(float* __restrict__ gsum, float* __restrict__ gcnt) {
    int i = blockIdx.x * blockDim.x + threadIdx.x;
    if (i < NG * HID) gsum[i] = 0.f;
    if (i < NG) gcnt[i] = 0.f;
}

// ------- hist: block (r,s) counts its node-range over its edge slice in LDS,
//         direct-stores per-slice partial counts. ZERO global atomics. -------
__global__ __launch_bounds__(CSR_T) void k_hist3(const int* __restrict__ dst,
                                                 int* __restrict__ partial) {
    const int r = blockIdx.x & (RS - 1);
    const int s = blockIdx.x >> 3;
    const int node0 = r * SUBN;
    __shared__ int lcnt[SUBN];                 // 50 KB
    for (int k = threadIdx.x; k < SUBN; k += CSR_T) lcnt[k] = 0;
    __syncthreads();
    const int g1 = (s + 1) * GPS;
    for (int g = s * GPS + threadIdx.x; g < g1; g += CSR_T) {
        const int4v d = *((const int4v*)dst + g);
        unsigned k;
        k = (unsigned)(d.x - node0); if (k < SUBN) atomicAdd(&lcnt[k], 1);
        k = (unsigned)(d.y - node0); if (k < SUBN) atomicAdd(&lcnt[k], 1);
        k = (unsigned)(d.z - node0); if (k < SUBN) atomicAdd(&lcnt[k], 1);
        k = (unsigned)(d.w - node0); if (k < SUBN) atomicAdd(&lcnt[k], 1);
    }
    __syncthreads();
    for (int k = threadIdx.x; k < SUBN; k += CSR_T)
        partial[s * NN + node0 + k] = lcnt[k];   // disjoint -> plain store
}

// ------- scanA: fold 32 partials/node -> total (+ in-place exclusive prefix
//         over slices), dinv, block-exclusive scan of totals -------
__global__ void k_scanA(int* __restrict__ partial, int* __restrict__ row_ptr,
                        int* __restrict__ bsum, float* __restrict__ dinv) {
    __shared__ int lds[SCAN_B];
    int i = blockIdx.x * SCAN_B + threadIdx.x;
    int v = 0;
    if (i < NN) {
        int run = 0;
#pragma unroll
        for (int s = 0; s < NSL; s++) {
            int c = partial[s * NN + i];
            partial[s * NN + i] = run;           // exclusive prefix (per node)
            run += c;
        }
        v = run;
        dinv[i] = rsqrtf((float)v + 1.0f);
    }
    lds[threadIdx.x] = v;
    __syncthreads();
    int val = v;
    for (int off = 1; off < SCAN_B; off <<= 1) {
        int u = 0;
        if ((int)threadIdx.x >= off) u = lds[threadIdx.x - off];
        __syncthreads();
        if ((int)threadIdx.x >= off) { val += u; lds[threadIdx.x] = val; }
        __syncthreads();
    }
    if (i < NN) row_ptr[i] = val - v;
    if (threadIdx.x == SCAN_B - 1) bsum[blockIdx.x] = val;
}

// ---------------- scanB: scan block sums ----------------
__global__ void k_scanB(int* __restrict__ bsum) {
    __shared__ int lds[128];
    int t = threadIdx.x;
    int v = (t < NB) ? bsum[t] : 0;
    lds[t] = v;
    __syncthreads();
    int val = v;
    for (int off = 1; off < 128; off <<= 1) {
        int u = 0;
        if (t >= off) u = lds[t - off];
        __syncthreads();
        if (t >= off) { val += u; lds[t] = val; }
        __syncthreads();
    }
    if (t < NB) bsum[t] = val - v;
}

// ---------------- scanC: add block offsets ----------------
__global__ void k_scanC(int* __restrict__ row_ptr, const int* __restrict__ bsum) {
    int i = blockIdx.x * SCAN_B + threadIdx.x;
    if (i < NN) row_ptr[i] += bsum[blockIdx.x];
    if (i == 0) row_ptr[NN] = NE;
}

// ------- scatter: LDS cursor = row_ptr + slice-prefix; per-edge position via
//         LDS atomic only; csr writes XCD-local (bid&7 == node range). -------
__global__ __launch_bounds__(CSR_T) void k_scat3(const int* __restrict__ src,
                                                 const int* __restrict__ dst,
                                                 const int* __restrict__ row_ptr,
                                                 const int* __restrict__ pref,
                                                 int* __restrict__ csr_src) {
    const int r = blockIdx.x & (RS - 1);
    const int s = blockIdx.x >> 3;
    const int node0 = r * SUBN;
    __shared__ int lcur[SUBN];                 // 50 KB
    for (int k = threadIdx.x; k < SUBN; k += CSR_T)
        lcur[k] = row_ptr[node0 + k] + pref[s * NN + node0 + k];
    __syncthreads();
    const int g1 = (s + 1) * GPS;
    for (int g = s * GPS + threadIdx.x; g < g1; g += CSR_T) {
        const int4v d = *((const int4v*)dst + g);
        const int4v sx = *((const int4v*)src + g);
        unsigned k;
        k = (unsigned)(d.x - node0); if (k < SUBN) { int p = atomicAdd(&lcur[k], 1); csr_src[p] = sx.x; }
        k = (unsigned)(d.y - node0); if (k < SUBN) { int p = atomicAdd(&lcur[k], 1); csr_src[p] = sx.y; }
        k = (unsigned)(d.z - node0); if (k < SUBN) { int p = atomicAdd(&lcur[k], 1); csr_src[p] = sx.z; }
        k = (unsigned)(d.w - node0); if (k < SUBN) { int p = atomicAdd(&lcur[k], 1); csr_src[p] = sx.w; }
    }
}

// ---------------- layer-0 GEMM via bf16 MFMA: t = bf16((x @ W0) * dinv) --------
__global__ void k_gemm0(const float* __restrict__ x, const float* __restrict__ W,
                        const float* __restrict__ dinv, unsigned short* __restrict__ t) {
    __shared__ __align__(16) unsigned short x_lds[G0_NODES][XPAD];
    __shared__ __align__(16) unsigned short wt_lds[HID][XPAD];
    const int tid = threadIdx.x;
    const int node0 = blockIdx.x * G0_NODES;

#pragma unroll
    for (int r = 0; r < 8; r++) {
        int q = tid + 256 * r;
        int row = q >> 5;
        int c4 = q & 31;
        float4 xv = {0.f, 0.f, 0.f, 0.f};
        int node = node0 + row;
        if (node < NN) xv = ((const float4*)(x + (size_t)node * FIN))[c4];
        ushort4 b;
        b.x = f2bf(xv.x); b.y = f2bf(xv.y); b.z = f2bf(xv.z); b.w = f2bf(xv.w);
        *(ushort4*)&x_lds[row][c4 * 4] = b;
    }
#pragma unroll
    for (int r = 0; r < 16; r++) {
        int q = tid + 256 * r;
        int k = q >> 5, n = q & 31;
        wt_lds[n][k] = f2bf(W[q]);
    }
    __syncthreads();

    const int w = tid >> 6;
    const int lane = tid & 63;
    const int row = lane & 15;
    const int kg = lane >> 4;
    const int w16 = w * 16;

    f32x4 acc0 = {0.f, 0.f, 0.f, 0.f};
    f32x4 acc1 = {0.f, 0.f, 0.f, 0.f};
#pragma unroll
    for (int s = 0; s < 4; s++) {
        short8 a  = *(const short8*)&x_lds[w16 + row][s * 32 + kg * 8];
        short8 b0 = *(const short8*)&wt_lds[row][s * 32 + kg * 8];
        short8 b1 = *(const short8*)&wt_lds[16 + row][s * 32 + kg * 8];
        acc0 = __builtin_amdgcn_mfma_f32_16x16x32_bf16(a, b0, acc0, 0, 0, 0);
        acc1 = __builtin_amdgcn_mfma_f32_16x16x32_bf16(a, b1, acc1, 0, 0, 0);
    }

    const int f = lane & 15;
#pragma unroll
    for (int j = 0; j < 4; j++) {
        int node = node0 + w16 + kg * 4 + j;
        if (node < NN) {
            float di = dinv[node];
            t[(size_t)node * HID + f]      = f2bf(acc0[j] * di);
            t[(size_t)node * HID + 16 + f] = f2bf(acc1[j] * di);
        }
    }
}

// ---------------- hidden GEMM: t = bf16((h @ W) * dinv) ----------------
__global__ void k_gemmh(const float* __restrict__ h, const float* __restrict__ W,
                        const float* __restrict__ dinv, unsigned short* __restrict__ t) {
    __shared__ float Ws[HID * HID];
    for (int j = threadIdx.x; j < HID * HID; j += 256) Ws[j] = W[j];
    __syncthreads();
    int gid = blockIdx.x * 256 + threadIdx.x;
    int i = gid >> 5, f = gid & 31;
    if (i >= NN) return;
    const float4* hr = (const float4*)(h + (size_t)i * HID);
    float acc = 0.f;
#pragma unroll
    for (int k4 = 0; k4 < HID / 4; k4++) {
        float4 hv = hr[k4];
        int kb = k4 * 4;
        acc = fmaf(hv.x, Ws[(kb + 0) * HID + f], acc);
        acc = fmaf(hv.y, Ws[(kb + 1) * HID + f], acc);
        acc = fmaf(hv.z, Ws[(kb + 2) * HID + f], acc);
        acc = fmaf(hv.w, Ws[(kb + 3) * HID + f], acc);
    }
    t[(size_t)i * HID + f] = f2bf(acc * dinv[i]);
}

// ------- aggregation: lane = feature, bf16 rows (one 64B line per gather) -------
__global__ void k_agg(const unsigned short* __restrict__ t, const int* __restrict__ row_ptr,
                      const int* __restrict__ csr_src, const float* __restrict__ dinv,
                      const float* __restrict__ b, float* __restrict__ hout) {
    int gid = blockIdx.x * blockDim.x + threadIdx.x;
    int i = gid >> 5;                 // node
    int lane = threadIdx.x & 31;      // feature
    if (i >= NN) return;
    float acc = bf2f(t[(size_t)i * HID + lane]);    // self term
    const int beg = row_ptr[i], end = row_ptr[i + 1];
    int e = beg;
    for (; e + 8 <= end; e += 8) {
        int s0 = csr_src[e + 0];
        int s1 = csr_src[e + 1];
        int s2 = csr_src[e + 2];
        int s3 = csr_src[e + 3];
        int s4 = csr_src[e + 4];
        int s5 = csr_src[e + 5];
        int s6 = csr_src[e + 6];
        int s7 = csr_src[e + 7];
        unsigned short u0 = t[(size_t)s0 * HID + lane];
        unsigned short u1 = t[(size_t)s1 * HID + lane];
        unsigned short u2 = t[(size_t)s2 * HID + lane];
        unsigned short u3 = t[(size_t)s3 * HID + lane];
        unsigned short u4 = t[(size_t)s4 * HID + lane];
        unsigned short u5 = t[(size_t)s5 * HID + lane];
        unsigned short u6 = t[(size_t)s6 * HID + lane];
        unsigned short u7 = t[(size_t)s7 * HID + lane];
        acc += ((bf2f(u0) + bf2f(u1)) + (bf2f(u2) + bf2f(u3)))
             + ((bf2f(u4) + bf2f(u5)) + (bf2f(u6) + bf2f(u7)));
    }
    for (; e + 4 <= end; e += 4) {
        int s0 = csr_src[e + 0];
        int s1 = csr_src[e + 1];
        int s2 = csr_src[e + 2];
        int s3 = csr_src[e + 3];
        unsigned short u0 = t[(size_t)s0 * HID + lane];
        unsigned short u1 = t[(size_t)s1 * HID + lane];
        unsigned short u2 = t[(size_t)s2 * HID + lane];
        unsigned short u3 = t[(size_t)s3 * HID + lane];
        acc += (bf2f(u0) + bf2f(u1)) + (bf2f(u2) + bf2f(u3));
    }
    for (; e < end; e++) {
        acc += bf2f(t[(size_t)csr_src[e] * HID + lane]);
    }
    float r = fmaf(acc, dinv[i], b[lane]);
    hout[(size_t)i * HID + lane] = fmaxf(r, 0.f);
}

// ---------------- pooling: register-segment accumulate -> LDS bins ----------
__global__ void k_pool2(const float* __restrict__ h, const int* __restrict__ batch,
                        float* __restrict__ gsum, float* __restrict__ gcnt) {
    __shared__ float lacc[POOL_GSPAN][HID];
    __shared__ float lcnt[POOL_GSPAN];
    __shared__ int s_gmin;
    const int chunk_start = blockIdx.x * POOL_CHUNK;

    for (int j = threadIdx.x; j < POOL_GSPAN * HID; j += 256) ((float*)lacc)[j] = 0.f;
    if (threadIdx.x < POOL_GSPAN) lcnt[threadIdx.x] = 0.f;
    if (threadIdx.x == 0) {
        int cs = chunk_start < NN ? chunk_start : NN - 1;
        s_gmin = batch[cs];
    }
    __syncthreads();
    const int gmin = s_gmin;

    const int seg = threadIdx.x >> 3;
    const int l = (threadIdx.x & 7) * 4;
    const int i0 = chunk_start + seg * POOL_SEG;

    float4 acc = {0.f, 0.f, 0.f, 0.f};
    float cnt = 0.f;
    int cur_g = -1;

    for (int k = 0; k < POOL_SEG; k++) {
        int i = i0 + k;
        if (i >= NN) break;
        int g = batch[i];
        if (g != cur_g) {
            if (cur_g >= 0) {
                int bin = cur_g - gmin;
                if (bin >= 0 && bin < POOL_GSPAN) {
                    atomicAdd(&lacc[bin][l + 0], acc.x);
                    atomicAdd(&lacc[bin][l + 1], acc.y);
                    atomicAdd(&lacc[bin][l + 2], acc.z);
                    atomicAdd(&lacc[bin][l + 3], acc.w);
                    if (l == 0) atomicAdd(&lcnt[bin], cnt);
                } else {
                    atomicAdd(&gsum[cur_g * HID + l + 0], acc.x);
                    atomicAdd(&gsum[cur_g * HID + l + 1], acc.y);
                    atomicAdd(&gsum[cur_g * HID + l + 2], acc.z);
                    atomicAdd(&gsum[cur_g * HID + l + 3], acc.w);
                    if (l == 0) atomicAdd(&gcnt[cur_g], cnt);
                }
            }
            cur_g = g;
            acc.x = acc.y = acc.z = acc.w = 0.f;
            cnt = 0.f;
        }
        const float4 v = *(const float4*)&h[(size_t)i * HID + l];
        acc.x += v.x; acc.y += v.y; acc.z += v.z; acc.w += v.w;
        cnt += 1.f;
    }
    if (cur_g >= 0) {
        int bin = cur_g - gmin;
        if (bin >= 0 && bin < POOL_GSPAN) {
            atomicAdd(&lacc[bin][l + 0], acc.x);
            atomicAdd(&lacc[bin][l + 1], acc.y);
            atomicAdd(&lacc[bin][l + 2], acc.z);
            atomicAdd(&lacc[bin][l + 3], acc.w);
            if (l == 0) atomicAdd(&lcnt[bin], cnt);
        } else {
            atomicAdd(&gsum[cur_g * HID + l + 0], acc.x);
            atomicAdd(&gsum[cur_g * HID + l + 1], acc.y);
            atomicAdd(&gsum[cur_g * HID + l + 2], acc.z);
            atomicAdd(&gsum[cur_g * HID + l + 3], acc.w);
            if (l == 0) atomicAdd(&gcnt[cur_g], cnt);
        }
    }
    __syncthreads();

    for (int j = threadIdx.x; j < POOL_GSPAN * HID; j += 256) {
        int bin = j / HID, f = j % HID;
        int g = gmin + bin;
        float v = lacc[bin][f];
        if (g < NG && v != 0.f) atomicAdd(&gsum[g * HID + f], v);
    }
    if (threadIdx.x < POOL_GSPAN) {
        int g = gmin + threadIdx.x;
        float c = lcnt[threadIdx.x];
        if (g < NG && c != 0.f) atomicAdd(&gcnt[g], c);
    }
}

// ---------------- classifier + log_softmax ----------------
__global__ void k_classify(const float* __restrict__ gsum, const float* __restrict__ gcnt,
                           const float* __restrict__ Wl, const float* __restrict__ bl,
                           float* __restrict__ out) {
    __shared__ float w[HID * NCLS];
    __shared__ float bb[NCLS];
    int t = threadIdx.x;
    for (int j = t; j < HID * NCLS; j += blockDim.x) w[j] = Wl[j];
    if (t < NCLS) bb[t] = bl[t];
    __syncthreads();
    if (t >= NG) return;
    float c = gcnt[t];
    c = c > 1.f ? c : 1.f;
    float p[HID];
#pragma unroll
    for (int k = 0; k < HID; k++) p[k] = gsum[t * HID + k] / c;
    float lg[NCLS];
    float m = -1e30f;
#pragma unroll
    for (int c2 = 0; c2 < NCLS; c2++) {
        float a = bb[c2];
#pragma unroll
        for (int k = 0; k < HID; k++) a = fmaf(p[k], w[k * NCLS + c2], a);
        a = a > 0.f ? a : 0.f;
        lg[c2] = a;
        m = fmaxf(m, a);
    }
    float s = 0.f;
#pragma unroll
    for (int c2 = 0; c2 < NCLS; c2++) s += expf(lg[c2] - m);
    float ls = logf(s);
#pragma unroll
    for (int c2 = 0; c2 < NCLS; c2++) out[t * NCLS + c2] = lg[c2] - m - ls;
}

extern "C" void kernel_launch(void* const* d_in, const int* in_sizes, int n_in,
                              void* d_out, int out_size, void* d_ws, size_t ws_size,
                              hipStream_t stream) {
    const float* x  = (const float*)d_in[0];
    const int* ei   = (const int*)d_in[1];
    const int* batch = (const int*)d_in[2];
    const float* W0 = (const float*)d_in[3];
    const float* b0 = (const float*)d_in[4];
    const float* W1 = (const float*)d_in[5];
    const float* b1 = (const float*)d_in[6];
    const float* W2 = (const float*)d_in[7];
    const float* b2 = (const float*)d_in[8];
    const float* Wl = (const float*)d_in[9];
    const float* bl = (const float*)d_in[10];
    float* out = (float*)d_out;

    const int* esrc = ei;
    const int* edst = ei + NE;

    char* ws = (char*)d_ws;
    size_t off = 0;
    auto alloc = [&](size_t bytes) -> void* {
        void* p = ws + off;
        off = (off + bytes + 511) & ~(size_t)511;
        return p;
    };
    int*   row_ptr = (int*)alloc((NN + 1) * sizeof(int));
    float* dinv    = (float*)alloc(NN * sizeof(float));
    int*   bsum    = (int*)alloc(256 * sizeof(int));
    int*   csr_src = (int*)alloc(NE * sizeof(int));
    unsigned short* tbuf = (unsigned short*)alloc((size_t)NN * HID * sizeof(unsigned short));
    float* hA      = (float*)alloc((size_t)NN * HID * sizeof(float));
    float* hB      = (float*)alloc((size_t)NN * HID * sizeof(float));
    float* gsum    = (float*)alloc(NG * HID * sizeof(float));
    float* gcnt    = (float*)alloc(NG * sizeof(float));
    (void)ws_size; (void)in_sizes; (void)n_in; (void)out_size;

    // partial/pref array [NSL][NN] (12.8 MB) aliases (tbuf,hA) — dead until
    // CSR build completes; tbuf is only written from k_gemm0 onward.
    int* partial = (int*)tbuf;

    // ---- CSR build: zero per-edge global atomics, 16 waves/CU ----
    k_init<<<17, 256, 0, stream>>>(gsum, gcnt);
    k_hist3<<<CSRGRID, CSR_T, 0, stream>>>(edst, partial);
    k_scanA<<<NB, SCAN_B, 0, stream>>>(partial, row_ptr, bsum, dinv);
    k_scanB<<<1, 128, 0, stream>>>(bsum);
    k_scanC<<<NB, SCAN_B, 0, stream>>>(row_ptr, bsum);
    k_scat3<<<CSRGRID, CSR_T, 0, stream>>>(esrc, edst, row_ptr, partial, csr_src);

    const int gemm_grid = (NN * HID + 255) / 256;
    const int agg_grid = (NN * 32 + 255) / 256;

    // ---- layer 0 (MFMA) ----
    k_gemm0<<<G0_GRID, 256, 0, stream>>>(x, W0, dinv, tbuf);
    k_agg<<<agg_grid, 256, 0, stream>>>(tbuf, row_ptr, csr_src, dinv, b0, hA);
    // ---- layer 1 ----
    k_gemmh<<<gemm_grid, 256, 0, stream>>>(hA, W1, dinv, tbuf);
    k_agg<<<agg_grid, 256, 0, stream>>>(tbuf, row_ptr, csr_src, dinv, b1, hB);
    // ---- layer 2 ----
    k_gemmh<<<gemm_grid, 256, 0, stream>>>(hB, W2, dinv, tbuf);
    k_agg<<<agg_grid, 256, 0, stream>>>(tbuf, row_ptr, csr_src, dinv, b2, hA);

    // ---- pooling + classifier ----
    k_pool2<<<POOL_GRID, 256, 0, stream>>>(hA, batch, gsum, gcnt);
    k_classify<<<1, 128, 0, stream>>>(gsum, gcnt, Wl, bl, out);
}